// Round 6
// baseline (1449.483 us; speedup 1.0000x reference)
//
#include <hip/hip_runtime.h>
#include <math.h>

typedef int i32x4 __attribute__((ext_vector_type(4)));
typedef float f32x4 __attribute__((ext_vector_type(4)));
typedef float f32x2 __attribute__((ext_vector_type(2)));

#define QMAXF 127.0f
#define EPSQ 1e-8f

__device__ __forceinline__ void gl_lds16(const void* g, void* l) {
  __builtin_amdgcn_global_load_lds(
      (const __attribute__((address_space(1))) unsigned int*)g,
      (__attribute__((address_space(3))) unsigned int*)l, 16, 0, 0);
}
__device__ __forceinline__ void gl_lds4(const void* g, void* l) {
  __builtin_amdgcn_global_load_lds(
      (const __attribute__((address_space(1))) unsigned int*)g,
      (__attribute__((address_space(3))) unsigned int*)l, 4, 0, 0);
}

// Group-of-128 symmetric int8 quant: fp32 in -> int8 q + transposed scales.
// Exact reference math in fp32 (max/127, maximum(.,eps), divide, rint, clip).
__global__ __launch_bounds__(256)
void qdq8(const float* __restrict__ in, char* __restrict__ q,
          float* __restrict__ sT, long n_groups, int gpr, int R) {
  long wid = (long)blockIdx.x * 4 + (threadIdx.x >> 6);
  if (wid >= n_groups) return;
  int lane = threadIdx.x & 63;
  long base = wid * 128 + lane * 2;
  f32x2 v = *(const f32x2*)(in + base);
  float m = fmaxf(fabsf(v.x), fabsf(v.y));
#pragma unroll
  for (int off = 32; off; off >>= 1) m = fmaxf(m, __shfl_xor(m, off));
  float s = fmaxf(m / QMAXF, EPSQ);
  int q0 = (int)fminf(fmaxf(rintf(v.x / s), -QMAXF), QMAXF);
  int q1 = (int)fminf(fmaxf(rintf(v.y / s), -QMAXF), QMAXF);
  *(unsigned short*)(q + base) =
      (unsigned short)((q0 & 0xff) | ((q1 & 0xff) << 8));
  if (lane == 0) {
    long row = wid / gpr;
    long gc = wid - row * gpr;
    sT[gc * (long)R + row] = s;
  }
}

// ---------------------------------------------------------------------------
// int8 GEMM tile: 128x128 output, BK=128 (= one quant group), 4 waves (2x2),
// single-buffered LDS with REGISTER-PREFETCH overlap: per group, all LDS
// fragments are pulled into registers, then next-group global_load_lds is
// issued BEFORE the MFMA/rescale phase so HBM latency hides under compute.
// Exact int32 MFMA per group, fp32 rescale. G4 XOR swizzle (r5, verified:
// conflicts 1e8 -> 2e6) on both sides.  __launch_bounds__(256,1) -> 256
// unified regs so acc stays VGPR-resident (no accvgpr round-trips).
// ---------------------------------------------------------------------------

// Fused gate/up GEMM + SwiGLU + hidden group-quant (group = tile's 128 cols).
__global__ __launch_bounds__(256, 1)
void gemm_gu_i8(const char* __restrict__ Aq, const char* __restrict__ Bg,
                const char* __restrict__ Bu,
                const float* __restrict__ sAT, const float* __restrict__ sGT,
                const float* __restrict__ sUT,
                char* __restrict__ Hq, float* __restrict__ sHT,
                int M, int N, int K, int NBN) {
  __shared__ char sA[16384];
  __shared__ char sBG[16384];
  __shared__ char sBU[16384];
  __shared__ float sSa[128], sSg[128], sSu[128];
  __shared__ float rmx[2][128];
  __shared__ float rs[128];

  const int tid = threadIdx.x;
  const int lane = tid & 63;
  const int wid = tid >> 6;
  const int wr = (wid >> 1) * 64;
  const int wc = (wid & 1) * 64;
  const int l15 = lane & 15, l16 = lane >> 4;

  const int nwg = gridDim.x;
  const int wg = ((int)blockIdx.x & 7) * (nwg >> 3) + ((int)blockIdx.x >> 3);
  const long m0 = (long)(wg / NBN) * 128;
  const long n0 = (long)(wg % NBN) * 128;

  // staging geometry: thread's chunk k (k=0..3): c = tid+256k, row = c>>3
  // (row step between k's = 32 -> uniform stride 32*K), swizzled col.
  const long row0 = tid >> 3;
  const int off0 = (((tid & 7) * 16)) ^ ((int)(row0 & 7) << 4);
  const long kstr = 32L * K;  // uniform row-block stride (bytes, i8)
  const char* gA0 = Aq + (m0 + row0) * K + off0;
  const char* gG0 = Bg + (n0 + row0) * K + off0;
  const char* gU0 = Bu + (n0 + row0) * K + off0;

  const float* pS0;
  const float* pS1;
  float* dS0;
  float* dS1;
  long st0 = 0, st1 = 0;
  if (wid < 2) {
    pS0 = sAT + m0 + tid; dS0 = &sSa[wid * 64]; st0 = M;
    pS1 = sUT + n0 + tid; dS1 = &sSu[wid * 64]; st1 = N;
  } else {
    pS0 = sGT + n0 + (tid - 128); dS0 = &sSg[(wid - 2) * 64]; st0 = N;
    pS1 = pS0; dS1 = dS0;
  }

  const int rdSwz = (l15 & 7) << 4;
  const int colK0 = (l16 * 16) ^ rdSwz;
  const int colK1 = (64 + l16 * 16) ^ rdSwz;

  f32x4 accg[4][4], accu[4][4];
#pragma unroll
  for (int i = 0; i < 4; i++)
#pragma unroll
    for (int j = 0; j < 4; j++) {
      accg[i][j] = (f32x4){0.f, 0.f, 0.f, 0.f};
      accu[i][j] = (f32x4){0.f, 0.f, 0.f, 0.f};
    }
  const i32x4 iz = {0, 0, 0, 0};
  const int KG = K >> 7;

  // prologue: stage group 0, advance pointers to group 1
#pragma unroll
  for (int k = 0; k < 4; k++) {
    gl_lds16(gA0 + k * kstr, &sA[tid * 16 + k * 4096]);
    gl_lds16(gG0 + k * kstr, &sBG[tid * 16 + k * 4096]);
    gl_lds16(gU0 + k * kstr, &sBU[tid * 16 + k * 4096]);
  }
  gA0 += 128; gG0 += 128; gU0 += 128;
  gl_lds4(pS0, dS0); pS0 += st0;
  if (wid < 2) { gl_lds4(pS1, dS1); pS1 += st1; }
  asm volatile("s_waitcnt vmcnt(0)" ::: "memory");
  __syncthreads();

  for (int g = 0; g < KG; ++g) {
    const bool pf = (g + 1 < KG);
    // ---- phase-1 reads: A frags, Bg frags, all scales -> registers
    i32x4 af[4][2], bgf[4][2];
#pragma unroll
    for (int i = 0; i < 4; i++) {
      const int rb = (wr + i * 16 + l15) * 128;
      af[i][0] = *(const i32x4*)&sA[rb + colK0];
      af[i][1] = *(const i32x4*)&sA[rb + colK1];
    }
#pragma unroll
    for (int j = 0; j < 4; j++) {
      const int rb = (wc + j * 16 + l15) * 128;
      bgf[j][0] = *(const i32x4*)&sBG[rb + colK0];
      bgf[j][1] = *(const i32x4*)&sBG[rb + colK1];
    }
    f32x4 sa4[4];
#pragma unroll
    for (int i = 0; i < 4; i++)
      sa4[i] = *(const f32x4*)&sSa[wr + i * 16 + l16 * 4];
    f32x4 sbg4, sbu4;
#pragma unroll
    for (int j = 0; j < 4; j++) {
      sbg4[j] = sSg[wc + j * 16 + l15];
      sbu4[j] = sSu[wc + j * 16 + l15];
    }
    __syncthreads();  // all waves done reading sA, sBG, scales
    if (pf) {
#pragma unroll
      for (int k = 0; k < 4; k++) {
        gl_lds16(gA0 + k * kstr, &sA[tid * 16 + k * 4096]);
        gl_lds16(gG0 + k * kstr, &sBG[tid * 16 + k * 4096]);
      }
      gA0 += 128; gG0 += 128;
      gl_lds4(pS0, dS0); pS0 += st0;
      if (wid < 2) { gl_lds4(pS1, dS1); pS1 += st1; }
    }
    // ---- gate MFMAs + rescale (A/Bg/scale staging in flight underneath)
#pragma unroll
    for (int j = 0; j < 4; j++)
#pragma unroll
      for (int i = 0; i < 4; i++) {
        i32x4 tg = __builtin_amdgcn_mfma_i32_16x16x64_i8(af[i][0], bgf[j][0], iz, 0, 0, 0);
        tg = __builtin_amdgcn_mfma_i32_16x16x64_i8(af[i][1], bgf[j][1], tg, 0, 0, 0);
        accg[i][j] += (sa4[i] * sbg4[j]) * __builtin_convertvector(tg, f32x4);
      }
    // ---- phase-2 reads: Bu frags (sBU untouched by staging so far)
    i32x4 buf_[4][2];
#pragma unroll
    for (int j = 0; j < 4; j++) {
      const int rb = (wc + j * 16 + l15) * 128;
      buf_[j][0] = *(const i32x4*)&sBU[rb + colK0];
      buf_[j][1] = *(const i32x4*)&sBU[rb + colK1];
    }
    __syncthreads();  // all waves done reading sBU
    if (pf) {
#pragma unroll
      for (int k = 0; k < 4; k++)
        gl_lds16(gU0 + k * kstr, &sBU[tid * 16 + k * 4096]);
      gU0 += 128;
    }
    // ---- up MFMAs + rescale (Bu staging in flight underneath)
#pragma unroll
    for (int j = 0; j < 4; j++)
#pragma unroll
      for (int i = 0; i < 4; i++) {
        i32x4 tu = __builtin_amdgcn_mfma_i32_16x16x64_i8(af[i][0], buf_[j][0], iz, 0, 0, 0);
        tu = __builtin_amdgcn_mfma_i32_16x16x64_i8(af[i][1], buf_[j][1], tu, 0, 0, 0);
        accu[i][j] += (sa4[i] * sbu4[j]) * __builtin_convertvector(tu, f32x4);
      }
    asm volatile("s_waitcnt vmcnt(0)" ::: "memory");
    __syncthreads();  // staged group g+1 fully resident
  }

  // ---- epilogue: h = silu(g)*u; per-row (128-col group) max -> s; quantize.
  float pm[4][4];
#pragma unroll
  for (int i = 0; i < 4; i++)
#pragma unroll
    for (int r = 0; r < 4; r++) pm[i][r] = 0.f;
#pragma unroll
  for (int i = 0; i < 4; i++)
#pragma unroll
    for (int j = 0; j < 4; j++)
#pragma unroll
      for (int r = 0; r < 4; r++) {
        float gv = accg[i][j][r];
        float h = gv / (1.f + expf(-gv)) * accu[i][j][r];
        accu[i][j][r] = h;
        pm[i][r] = fmaxf(pm[i][r], fabsf(h));
      }
#pragma unroll
  for (int i = 0; i < 4; i++)
#pragma unroll
    for (int r = 0; r < 4; r++) {
      pm[i][r] = fmaxf(pm[i][r], __shfl_xor(pm[i][r], 1));
      pm[i][r] = fmaxf(pm[i][r], __shfl_xor(pm[i][r], 2));
      pm[i][r] = fmaxf(pm[i][r], __shfl_xor(pm[i][r], 4));
      pm[i][r] = fmaxf(pm[i][r], __shfl_xor(pm[i][r], 8));
    }
#pragma unroll
  for (int i = 0; i < 4; i++)
#pragma unroll
    for (int r = 0; r < 4; r++)
      if (l15 == i * 4 + r) rmx[wid & 1][wr + i * 16 + l16 * 4 + r] = pm[i][r];
  __syncthreads();
  if (tid < 128) {
    float mx = fmaxf(rmx[0][tid], rmx[1][tid]);
    float s = fmaxf(mx / QMAXF, EPSQ);
    rs[tid] = s;
    sHT[(n0 >> 7) * (long)M + m0 + tid] = s;
  }
  __syncthreads();
#pragma unroll
  for (int i = 0; i < 4; i++) {
    f32x4 sr = *(const f32x4*)&rs[wr + i * 16 + l16 * 4];
#pragma unroll
    for (int j = 0; j < 4; j++)
#pragma unroll
      for (int r = 0; r < 4; r++) {
        float qv = fminf(fmaxf(rintf(accu[i][j][r] / sr[r]), -QMAXF), QMAXF);
        sA[(wr + i * 16 + l16 * 4 + r) * 128 + wc + j * 16 + l15] = (char)(int)qv;
      }
  }
  __syncthreads();
  {
    int row = tid >> 1, seg = tid & 1;
    const i32x4* src = (const i32x4*)&sA[row * 128 + seg * 64];
    i32x4* dst = (i32x4*)(Hq + (m0 + row) * N + n0 + seg * 64);
#pragma unroll
    for (int k = 0; k < 4; k++) dst[k] = src[k];
  }
}

// Down GEMM: fp32 out = dequant(A_i8) . dequant(B_i8)^T with exact int cores.
__global__ __launch_bounds__(256, 1)
void gemm_dn_i8(const char* __restrict__ Aq, const char* __restrict__ Bq,
                const float* __restrict__ sAT, const float* __restrict__ sBT,
                float* __restrict__ C, int M, int N, int K, int NBN) {
  __shared__ char sA[16384];
  __shared__ char sB[16384];
  __shared__ float sSa[128], sSb[128];

  const int tid = threadIdx.x;
  const int lane = tid & 63;
  const int wid = tid >> 6;
  const int wr = (wid >> 1) * 64;
  const int wc = (wid & 1) * 64;
  const int l15 = lane & 15, l16 = lane >> 4;

  const int nwg = gridDim.x;
  const int wg = ((int)blockIdx.x & 7) * (nwg >> 3) + ((int)blockIdx.x >> 3);
  const long m0 = (long)(wg / NBN) * 128;
  const long n0 = (long)(wg % NBN) * 128;

  const long row0 = tid >> 3;
  const int off0 = (((tid & 7) * 16)) ^ ((int)(row0 & 7) << 4);
  const long kstr = 32L * K;
  const char* gA0 = Aq + (m0 + row0) * K + off0;
  const char* gB0 = Bq + (n0 + row0) * K + off0;

  const float* pS0;
  float* dS0;
  long st0;
  if (wid < 2) {
    pS0 = sAT + m0 + tid; dS0 = &sSa[wid * 64]; st0 = M;
  } else {
    pS0 = sBT + n0 + (tid - 128); dS0 = &sSb[(wid - 2) * 64]; st0 = N;
  }

  const int rdSwz = (l15 & 7) << 4;
  const int colK0 = (l16 * 16) ^ rdSwz;
  const int colK1 = (64 + l16 * 16) ^ rdSwz;

  f32x4 acc[4][4];
#pragma unroll
  for (int i = 0; i < 4; i++)
#pragma unroll
    for (int j = 0; j < 4; j++) acc[i][j] = (f32x4){0.f, 0.f, 0.f, 0.f};
  const i32x4 iz = {0, 0, 0, 0};
  const int KG = K >> 7;

#pragma unroll
  for (int k = 0; k < 4; k++) {
    gl_lds16(gA0 + k * kstr, &sA[tid * 16 + k * 4096]);
    gl_lds16(gB0 + k * kstr, &sB[tid * 16 + k * 4096]);
  }
  gA0 += 128; gB0 += 128;
  gl_lds4(pS0, dS0); pS0 += st0;
  asm volatile("s_waitcnt vmcnt(0)" ::: "memory");
  __syncthreads();

  for (int g = 0; g < KG; ++g) {
    const bool pf = (g + 1 < KG);
    i32x4 af[4][2], bf[4][2];
#pragma unroll
    for (int i = 0; i < 4; i++) {
      const int rb = (wr + i * 16 + l15) * 128;
      af[i][0] = *(const i32x4*)&sA[rb + colK0];
      af[i][1] = *(const i32x4*)&sA[rb + colK1];
    }
#pragma unroll
    for (int j = 0; j < 4; j++) {
      const int rb = (wc + j * 16 + l15) * 128;
      bf[j][0] = *(const i32x4*)&sB[rb + colK0];
      bf[j][1] = *(const i32x4*)&sB[rb + colK1];
    }
    f32x4 sa4[4];
#pragma unroll
    for (int i = 0; i < 4; i++)
      sa4[i] = *(const f32x4*)&sSa[wr + i * 16 + l16 * 4];
    f32x4 sb4;
#pragma unroll
    for (int j = 0; j < 4; j++) sb4[j] = sSb[wc + j * 16 + l15];
    __syncthreads();  // all waves done reading LDS for group g
    if (pf) {
#pragma unroll
      for (int k = 0; k < 4; k++) {
        gl_lds16(gA0 + k * kstr, &sA[tid * 16 + k * 4096]);
        gl_lds16(gB0 + k * kstr, &sB[tid * 16 + k * 4096]);
      }
      gA0 += 128; gB0 += 128;
      gl_lds4(pS0, dS0); pS0 += st0;
    }
    // MFMA + rescale with staging in flight underneath
#pragma unroll
    for (int j = 0; j < 4; j++)
#pragma unroll
      for (int i = 0; i < 4; i++) {
        i32x4 t = __builtin_amdgcn_mfma_i32_16x16x64_i8(af[i][0], bf[j][0], iz, 0, 0, 0);
        t = __builtin_amdgcn_mfma_i32_16x16x64_i8(af[i][1], bf[j][1], t, 0, 0, 0);
        acc[i][j] += (sa4[i] * sb4[j]) * __builtin_convertvector(t, f32x4);
      }
    asm volatile("s_waitcnt vmcnt(0)" ::: "memory");
    __syncthreads();
  }

#pragma unroll
  for (int i = 0; i < 4; i++)
#pragma unroll
    for (int j = 0; j < 4; j++)
#pragma unroll
      for (int r = 0; r < 4; r++) {
        long row = m0 + wr + i * 16 + l16 * 4 + r;
        long col = n0 + wc + j * 16 + l15;
        C[row * N + col] = acc[i][j][r];
      }
}

extern "C" void kernel_launch(void* const* d_in, const int* in_sizes, int n_in,
                              void* d_out, int out_size, void* d_ws, size_t ws_size,
                              hipStream_t stream) {
  (void)n_in; (void)out_size;
  const float* x  = (const float*)d_in[0];
  const float* wg = (const float*)d_in[1];
  const float* wu = (const float*)d_in[2];
  const float* wd = (const float*)d_in[3];
  float* out = (float*)d_out;

  const long H = 4096;
  const long M = in_sizes[0] / H;   // 4096 (B*S)
  const long I = in_sizes[1] / H;   // 11008
  const long GH = H >> 7;           // 32
  const long GI = I >> 7;           // 86

  char* ws = (char*)d_ws;
  size_t off = 0;
  char* xq  = ws + off; off += (size_t)(M * H);
  char* wgq = ws + off; off += (size_t)(I * H);
  char* wuq = ws + off; off += (size_t)(I * H);
  char* wdq = ws + off; off += (size_t)(H * I);
  char* hq  = ws + off; off += (size_t)(M * I);
  float* s_x = (float*)(ws + off); off += (size_t)(GH * M) * 4;
  float* s_g = (float*)(ws + off); off += (size_t)(GH * I) * 4;
  float* s_u = (float*)(ws + off); off += (size_t)(GH * I) * 4;
  float* s_d = (float*)(ws + off); off += (size_t)(GI * H) * 4;
  float* s_h = (float*)(ws + off); off += (size_t)(GI * M) * 4;
  if (ws_size < off) return;

  // 1) int8 group-quant of inputs/weights (q + transposed scales)
  {
    long ng;
    ng = M * H / 128;
    qdq8<<<dim3((unsigned)((ng + 3) / 4)), dim3(256), 0, stream>>>(x, xq, s_x, ng, (int)GH, (int)M);
    ng = I * H / 128;
    qdq8<<<dim3((unsigned)((ng + 3) / 4)), dim3(256), 0, stream>>>(wg, wgq, s_g, ng, (int)GH, (int)I);
    qdq8<<<dim3((unsigned)((ng + 3) / 4)), dim3(256), 0, stream>>>(wu, wuq, s_u, ng, (int)GH, (int)I);
    ng = H * I / 128;
    qdq8<<<dim3((unsigned)((ng + 3) / 4)), dim3(256), 0, stream>>>(wd, wdq, s_d, ng, (int)GI, (int)H);
  }

  // 2) fused gate/up int8 GEMM + SwiGLU + hidden quant -> hq, s_h
  {
    const int NBN = (int)GI;                       // 86
    const int grid = (int)(M / 128) * NBN;         // 2752 (%8==0)
    gemm_gu_i8<<<dim3(grid), dim3(256), 0, stream>>>(
        xq, wgq, wuq, s_x, s_g, s_u, hq, s_h, (int)M, (int)I, (int)H, NBN);
  }
  // 3) down int8 GEMM -> fp32 out
  {
    const int NBN = (int)GH;                       // 32
    const int grid = (int)(M / 128) * NBN;         // 1024 (%8==0)
    gemm_dn_i8<<<dim3(grid), dim3(256), 0, stream>>>(
        hq, wdq, s_h, s_d, out, (int)M, (int)H, (int)I, NBN);
  }
}

// Round 7
// 1167.925 us; speedup vs baseline: 1.2411x; 1.2411x over previous
//
#include <hip/hip_runtime.h>
#include <math.h>

typedef int i32x4 __attribute__((ext_vector_type(4)));
typedef float f32x4 __attribute__((ext_vector_type(4)));
typedef float f32x2 __attribute__((ext_vector_type(2)));

#define QMAXF 127.0f
#define EPSQ 1e-8f

__device__ __forceinline__ void gl_lds16(const void* g, void* l) {
  __builtin_amdgcn_global_load_lds(
      (const __attribute__((address_space(1))) unsigned int*)g,
      (__attribute__((address_space(3))) unsigned int*)l, 16, 0, 0);
}
__device__ __forceinline__ void gl_lds4(const void* g, void* l) {
  __builtin_amdgcn_global_load_lds(
      (const __attribute__((address_space(1))) unsigned int*)g,
      (__attribute__((address_space(3))) unsigned int*)l, 4, 0, 0);
}

// Group-of-128 symmetric int8 quant: fp32 in -> int8 q + transposed scales.
// Exact reference math in fp32 (max/127, maximum(.,eps), divide, rint, clip).
__global__ __launch_bounds__(256)
void qdq8(const float* __restrict__ in, char* __restrict__ q,
          float* __restrict__ sT, long n_groups, int gpr, int R) {
  long wid = (long)blockIdx.x * 4 + (threadIdx.x >> 6);
  if (wid >= n_groups) return;
  int lane = threadIdx.x & 63;
  long base = wid * 128 + lane * 2;
  f32x2 v = *(const f32x2*)(in + base);
  float m = fmaxf(fabsf(v.x), fabsf(v.y));
#pragma unroll
  for (int off = 32; off; off >>= 1) m = fmaxf(m, __shfl_xor(m, off));
  float s = fmaxf(m / QMAXF, EPSQ);
  int q0 = (int)fminf(fmaxf(rintf(v.x / s), -QMAXF), QMAXF);
  int q1 = (int)fminf(fmaxf(rintf(v.y / s), -QMAXF), QMAXF);
  *(unsigned short*)(q + base) =
      (unsigned short)((q0 & 0xff) | ((q1 & 0xff) << 8));
  if (lane == 0) {
    long row = wid / gpr;
    long gc = wid - row * gpr;
    sT[gc * (long)R + row] = s;
  }
}

// ---------------------------------------------------------------------------
// int8 GEMM tile: 128x128 output, BK=128 (= one quant group), 4 waves (2x2),
// single-buffered LDS (r5-proven skeleton, best measured). Exact int32 MFMA
// per group, fp32 rescale. G4 XOR swizzle on both sides (verified r5:
// conflicts 1e8 -> 2e6).
// amdgpu_waves_per_eu(2,2): pin register budget to 256/wave so the 128-float
// accumulator is VGPR-resident (no v_accvgpr_read/write shuttle around the
// per-group rescale). Runtime occupancy equals r5's measured 2 blocks/CU.
// ---------------------------------------------------------------------------

// Fused gate/up GEMM + SwiGLU + hidden group-quant (group = tile's 128 cols).
__global__ __launch_bounds__(256) __attribute__((amdgpu_waves_per_eu(2, 2)))
void gemm_gu_i8(const char* __restrict__ Aq, const char* __restrict__ Bg,
                const char* __restrict__ Bu,
                const float* __restrict__ sAT, const float* __restrict__ sGT,
                const float* __restrict__ sUT,
                char* __restrict__ Hq, float* __restrict__ sHT,
                int M, int N, int K, int NBN) {
  __shared__ char sA[16384];
  __shared__ char sBG[16384];
  __shared__ char sBU[16384];
  __shared__ float sSa[128], sSg[128], sSu[128];
  __shared__ float rmx[2][128];
  __shared__ float rs[128];

  const int tid = threadIdx.x;
  const int lane = tid & 63;
  const int wid = tid >> 6;
  const int wr = (wid >> 1) * 64;
  const int wc = (wid & 1) * 64;
  const int l15 = lane & 15, l16 = lane >> 4;

  const int nwg = gridDim.x;
  const int wg = ((int)blockIdx.x & 7) * (nwg >> 3) + ((int)blockIdx.x >> 3);
  const long m0 = (long)(wg / NBN) * 128;
  const long n0 = (long)(wg % NBN) * 128;

  // staging: 1024 x 16B chunks per 16KB tile; thread stages c = tid + 256k.
  // chunk c -> phys (row = c>>3, pcol = (c&7)*16); global col = pcol ^ swz(row).
  const char* gA[4];
  const char* gG[4];
  const char* gU[4];
#pragma unroll
  for (int k = 0; k < 4; k++) {
    int c = tid + 256 * k;
    long row = c >> 3;
    int off = ((c & 7) * 16) ^ ((int)(row & 7) << 4);
    gA[k] = Aq + (m0 + row) * K + off;
    gG[k] = Bg + (n0 + row) * K + off;
    gU[k] = Bu + (n0 + row) * K + off;
  }

  // fragment read col fields (logical kk*64 + l16*16, XOR'd by row swizzle)
  const int rdSwz = (l15 & 7) << 4;
  const int colK0 = (l16 * 16) ^ rdSwz;
  const int colK1 = (64 + l16 * 16) ^ rdSwz;

  f32x4 accg[4][4], accu[4][4];
#pragma unroll
  for (int i = 0; i < 4; i++)
#pragma unroll
    for (int j = 0; j < 4; j++) {
      accg[i][j] = (f32x4){0.f, 0.f, 0.f, 0.f};
      accu[i][j] = (f32x4){0.f, 0.f, 0.f, 0.f};
    }
  const i32x4 iz = {0, 0, 0, 0};

  const int KG = K >> 7;
  for (int g = 0; g < KG; ++g) {
    const long kb = (long)g << 7;
#pragma unroll
    for (int k = 0; k < 4; k++) {
      gl_lds16(gA[k] + kb, &sA[(tid + 256 * k) * 16]);
      gl_lds16(gG[k] + kb, &sBG[(tid + 256 * k) * 16]);
      gl_lds16(gU[k] + kb, &sBU[(tid + 256 * k) * 16]);
    }
    // group scales (contiguous, transposed layout). waves 0-1: sSa+sSu,
    // waves 2-3: sSg. lds base wave-uniform, global per-lane (m104 rule).
    if (wid < 2) {
      gl_lds4(sAT + (long)g * M + m0 + tid, &sSa[wid * 64]);
      gl_lds4(sUT + (long)g * N + n0 + tid, &sSu[wid * 64]);
    } else {
      gl_lds4(sGT + (long)g * N + n0 + (tid - 128), &sSg[(wid - 2) * 64]);
    }
    __syncthreads();

    i32x4 af[4][2];
#pragma unroll
    for (int i = 0; i < 4; i++) {
      const int rb = (wr + i * 16 + l15) * 128;
      af[i][0] = *(const i32x4*)&sA[rb + colK0];
      af[i][1] = *(const i32x4*)&sA[rb + colK1];
    }
    f32x4 sa4[4];
#pragma unroll
    for (int i = 0; i < 4; i++)
      sa4[i] = *(const f32x4*)&sSa[wr + i * 16 + l16 * 4];

#pragma unroll
    for (int j = 0; j < 4; j++) {
      const int rbB = (wc + j * 16 + l15) * 128;
      i32x4 bgf[2], buf_[2];
      bgf[0] = *(const i32x4*)&sBG[rbB + colK0];
      bgf[1] = *(const i32x4*)&sBG[rbB + colK1];
      buf_[0] = *(const i32x4*)&sBU[rbB + colK0];
      buf_[1] = *(const i32x4*)&sBU[rbB + colK1];
      float sbg = sSg[wc + j * 16 + l15];
      float sbu = sSu[wc + j * 16 + l15];
#pragma unroll
      for (int i = 0; i < 4; i++) {
        i32x4 tg = __builtin_amdgcn_mfma_i32_16x16x64_i8(af[i][0], bgf[0], iz, 0, 0, 0);
        tg = __builtin_amdgcn_mfma_i32_16x16x64_i8(af[i][1], bgf[1], tg, 0, 0, 0);
        i32x4 tu = __builtin_amdgcn_mfma_i32_16x16x64_i8(af[i][0], buf_[0], iz, 0, 0, 0);
        tu = __builtin_amdgcn_mfma_i32_16x16x64_i8(af[i][1], buf_[1], tu, 0, 0, 0);
        f32x4 mg = sa4[i] * sbg;
        f32x4 mu = sa4[i] * sbu;
        accg[i][j] += mg * __builtin_convertvector(tg, f32x4);
        accu[i][j] += mu * __builtin_convertvector(tu, f32x4);
      }
    }
    __syncthreads();
  }

  // ---- epilogue: h = silu(g)*u; per-row (128-col group) max -> s; quantize.
  // C/D map: col = l15, row(local) = wr + i*16 + l16*4 + r.
  float pm[4][4];
#pragma unroll
  for (int i = 0; i < 4; i++)
#pragma unroll
    for (int r = 0; r < 4; r++) pm[i][r] = 0.f;
#pragma unroll
  for (int i = 0; i < 4; i++)
#pragma unroll
    for (int j = 0; j < 4; j++)
#pragma unroll
      for (int r = 0; r < 4; r++) {
        float gv = accg[i][j][r];
        float h = gv / (1.f + expf(-gv)) * accu[i][j][r];
        accu[i][j][r] = h;
        pm[i][r] = fmaxf(pm[i][r], fabsf(h));
      }
  // reduce over the 16 l15-lanes (same row set)
#pragma unroll
  for (int i = 0; i < 4; i++)
#pragma unroll
    for (int r = 0; r < 4; r++) {
      pm[i][r] = fmaxf(pm[i][r], __shfl_xor(pm[i][r], 1));
      pm[i][r] = fmaxf(pm[i][r], __shfl_xor(pm[i][r], 2));
      pm[i][r] = fmaxf(pm[i][r], __shfl_xor(pm[i][r], 4));
      pm[i][r] = fmaxf(pm[i][r], __shfl_xor(pm[i][r], 8));
    }
#pragma unroll
  for (int i = 0; i < 4; i++)
#pragma unroll
    for (int r = 0; r < 4; r++)
      if (l15 == i * 4 + r) rmx[wid & 1][wr + i * 16 + l16 * 4 + r] = pm[i][r];
  __syncthreads();
  if (tid < 128) {
    float mx = fmaxf(rmx[0][tid], rmx[1][tid]);
    float s = fmaxf(mx / QMAXF, EPSQ);
    rs[tid] = s;
    sHT[(n0 >> 7) * (long)M + m0 + tid] = s;
  }
  __syncthreads();
  // quantize into sA (reused as transpose buffer), then coalesced copy out
#pragma unroll
  for (int i = 0; i < 4; i++) {
    f32x4 sr = *(const f32x4*)&rs[wr + i * 16 + l16 * 4];
#pragma unroll
    for (int j = 0; j < 4; j++)
#pragma unroll
      for (int r = 0; r < 4; r++) {
        float qv = fminf(fmaxf(rintf(accu[i][j][r] / sr[r]), -QMAXF), QMAXF);
        sA[(wr + i * 16 + l16 * 4 + r) * 128 + wc + j * 16 + l15] = (char)(int)qv;
      }
  }
  __syncthreads();
  {
    int row = tid >> 1, seg = tid & 1;
    const i32x4* src = (const i32x4*)&sA[row * 128 + seg * 64];
    i32x4* dst = (i32x4*)(Hq + (m0 + row) * N + n0 + seg * 64);
#pragma unroll
    for (int k = 0; k < 4; k++) dst[k] = src[k];
  }
}

// Down GEMM: fp32 out = dequant(A_i8) . dequant(B_i8)^T with exact int cores.
__global__ __launch_bounds__(256) __attribute__((amdgpu_waves_per_eu(2, 2)))
void gemm_dn_i8(const char* __restrict__ Aq, const char* __restrict__ Bq,
                const float* __restrict__ sAT, const float* __restrict__ sBT,
                float* __restrict__ C, int M, int N, int K, int NBN) {
  __shared__ char sA[16384];
  __shared__ char sB[16384];
  __shared__ float sSa[128], sSb[128];

  const int tid = threadIdx.x;
  const int lane = tid & 63;
  const int wid = tid >> 6;
  const int wr = (wid >> 1) * 64;
  const int wc = (wid & 1) * 64;
  const int l15 = lane & 15, l16 = lane >> 4;

  const int nwg = gridDim.x;
  const int wg = ((int)blockIdx.x & 7) * (nwg >> 3) + ((int)blockIdx.x >> 3);
  const long m0 = (long)(wg / NBN) * 128;
  const long n0 = (long)(wg % NBN) * 128;

  const char* gA[4];
  const char* gB[4];
#pragma unroll
  for (int k = 0; k < 4; k++) {
    int c = tid + 256 * k;
    long row = c >> 3;
    int off = ((c & 7) * 16) ^ ((int)(row & 7) << 4);
    gA[k] = Aq + (m0 + row) * K + off;
    gB[k] = Bq + (n0 + row) * K + off;
  }

  const int rdSwz = (l15 & 7) << 4;
  const int colK0 = (l16 * 16) ^ rdSwz;
  const int colK1 = (64 + l16 * 16) ^ rdSwz;

  f32x4 acc[4][4];
#pragma unroll
  for (int i = 0; i < 4; i++)
#pragma unroll
    for (int j = 0; j < 4; j++) acc[i][j] = (f32x4){0.f, 0.f, 0.f, 0.f};
  const i32x4 iz = {0, 0, 0, 0};

  const int KG = K >> 7;
  for (int g = 0; g < KG; ++g) {
    const long kb = (long)g << 7;
#pragma unroll
    for (int k = 0; k < 4; k++) {
      gl_lds16(gA[k] + kb, &sA[(tid + 256 * k) * 16]);
      gl_lds16(gB[k] + kb, &sB[(tid + 256 * k) * 16]);
    }
    if (wid < 2) {
      gl_lds4(sAT + (long)g * M + m0 + tid, &sSa[wid * 64]);
    } else {
      gl_lds4(sBT + (long)g * N + n0 + (tid - 128), &sSb[(wid - 2) * 64]);
    }
    __syncthreads();

    i32x4 af[4][2];
#pragma unroll
    for (int i = 0; i < 4; i++) {
      const int rb = (wr + i * 16 + l15) * 128;
      af[i][0] = *(const i32x4*)&sA[rb + colK0];
      af[i][1] = *(const i32x4*)&sA[rb + colK1];
    }
    f32x4 sa4[4];
#pragma unroll
    for (int i = 0; i < 4; i++)
      sa4[i] = *(const f32x4*)&sSa[wr + i * 16 + l16 * 4];

#pragma unroll
    for (int j = 0; j < 4; j++) {
      const int rbB = (wc + j * 16 + l15) * 128;
      i32x4 bf[2];
      bf[0] = *(const i32x4*)&sB[rbB + colK0];
      bf[1] = *(const i32x4*)&sB[rbB + colK1];
      float sb = sSb[wc + j * 16 + l15];
#pragma unroll
      for (int i = 0; i < 4; i++) {
        i32x4 t = __builtin_amdgcn_mfma_i32_16x16x64_i8(af[i][0], bf[0], iz, 0, 0, 0);
        t = __builtin_amdgcn_mfma_i32_16x16x64_i8(af[i][1], bf[1], t, 0, 0, 0);
        f32x4 ms = sa4[i] * sb;
        acc[i][j] += ms * __builtin_convertvector(t, f32x4);
      }
    }
    __syncthreads();
  }

#pragma unroll
  for (int i = 0; i < 4; i++)
#pragma unroll
    for (int j = 0; j < 4; j++)
#pragma unroll
      for (int r = 0; r < 4; r++) {
        long row = m0 + wr + i * 16 + l16 * 4 + r;
        long col = n0 + wc + j * 16 + l15;
        C[row * N + col] = acc[i][j][r];
      }
}

extern "C" void kernel_launch(void* const* d_in, const int* in_sizes, int n_in,
                              void* d_out, int out_size, void* d_ws, size_t ws_size,
                              hipStream_t stream) {
  (void)n_in; (void)out_size;
  const float* x  = (const float*)d_in[0];
  const float* wg = (const float*)d_in[1];
  const float* wu = (const float*)d_in[2];
  const float* wd = (const float*)d_in[3];
  float* out = (float*)d_out;

  const long H = 4096;
  const long M = in_sizes[0] / H;   // 4096 (B*S)
  const long I = in_sizes[1] / H;   // 11008
  const long GH = H >> 7;           // 32
  const long GI = I >> 7;           // 86

  char* ws = (char*)d_ws;
  size_t off = 0;
  char* xq  = ws + off; off += (size_t)(M * H);
  char* wgq = ws + off; off += (size_t)(I * H);
  char* wuq = ws + off; off += (size_t)(I * H);
  char* wdq = ws + off; off += (size_t)(H * I);
  char* hq  = ws + off; off += (size_t)(M * I);
  float* s_x = (float*)(ws + off); off += (size_t)(GH * M) * 4;
  float* s_g = (float*)(ws + off); off += (size_t)(GH * I) * 4;
  float* s_u = (float*)(ws + off); off += (size_t)(GH * I) * 4;
  float* s_d = (float*)(ws + off); off += (size_t)(GI * H) * 4;
  float* s_h = (float*)(ws + off); off += (size_t)(GI * M) * 4;
  if (ws_size < off) return;

  // 1) int8 group-quant of inputs/weights (q + transposed scales)
  {
    long ng;
    ng = M * H / 128;
    qdq8<<<dim3((unsigned)((ng + 3) / 4)), dim3(256), 0, stream>>>(x, xq, s_x, ng, (int)GH, (int)M);
    ng = I * H / 128;
    qdq8<<<dim3((unsigned)((ng + 3) / 4)), dim3(256), 0, stream>>>(wg, wgq, s_g, ng, (int)GH, (int)I);
    qdq8<<<dim3((unsigned)((ng + 3) / 4)), dim3(256), 0, stream>>>(wu, wuq, s_u, ng, (int)GH, (int)I);
    ng = H * I / 128;
    qdq8<<<dim3((unsigned)((ng + 3) / 4)), dim3(256), 0, stream>>>(wd, wdq, s_d, ng, (int)GI, (int)H);
  }

  // 2) fused gate/up int8 GEMM + SwiGLU + hidden quant -> hq, s_h
  {
    const int NBN = (int)GI;                       // 86
    const int grid = (int)(M / 128) * NBN;         // 2752 (%8==0)
    gemm_gu_i8<<<dim3(grid), dim3(256), 0, stream>>>(
        xq, wgq, wuq, s_x, s_g, s_u, hq, s_h, (int)M, (int)I, (int)H, NBN);
  }
  // 3) down int8 GEMM -> fp32 out
  {
    const int NBN = (int)GH;                       // 32
    const int grid = (int)(M / 128) * NBN;         // 1024 (%8==0)
    gemm_dn_i8<<<dim3(grid), dim3(256), 0, stream>>>(
        hq, wdq, s_h, s_d, out, (int)M, (int)H, (int)I, NBN);
  }
}

// Round 8
// 1116.710 us; speedup vs baseline: 1.2980x; 1.0459x over previous
//
#include <hip/hip_runtime.h>
#include <math.h>

typedef int i32x4 __attribute__((ext_vector_type(4)));
typedef float f32x4 __attribute__((ext_vector_type(4)));
typedef float f32x2 __attribute__((ext_vector_type(2)));

#define QMAXF 127.0f
#define EPSQ 1e-8f

__device__ __forceinline__ void gl_lds16(const void* g, void* l) {
  __builtin_amdgcn_global_load_lds(
      (const __attribute__((address_space(1))) unsigned int*)g,
      (__attribute__((address_space(3))) unsigned int*)l, 16, 0, 0);
}
__device__ __forceinline__ void gl_lds4(const void* g, void* l) {
  __builtin_amdgcn_global_load_lds(
      (const __attribute__((address_space(1))) unsigned int*)g,
      (__attribute__((address_space(3))) unsigned int*)l, 4, 0, 0);
}

// Group-of-128 symmetric int8 quant: fp32 in -> int8 q + transposed scales.
// Exact reference math in fp32 (max/127, maximum(.,eps), divide, rint, clip).
__global__ __launch_bounds__(256)
void qdq8(const float* __restrict__ in, char* __restrict__ q,
          float* __restrict__ sT, long n_groups, int gpr, int R) {
  long wid = (long)blockIdx.x * 4 + (threadIdx.x >> 6);
  if (wid >= n_groups) return;
  int lane = threadIdx.x & 63;
  long base = wid * 128 + lane * 2;
  f32x2 v = *(const f32x2*)(in + base);
  float m = fmaxf(fabsf(v.x), fabsf(v.y));
#pragma unroll
  for (int off = 32; off; off >>= 1) m = fmaxf(m, __shfl_xor(m, off));
  float s = fmaxf(m / QMAXF, EPSQ);
  int q0 = (int)fminf(fmaxf(rintf(v.x / s), -QMAXF), QMAXF);
  int q1 = (int)fminf(fmaxf(rintf(v.y / s), -QMAXF), QMAXF);
  *(unsigned short*)(q + base) =
      (unsigned short)((q0 & 0xff) | ((q1 & 0xff) << 8));
  if (lane == 0) {
    long row = wid / gpr;
    long gc = wid - row * gpr;
    sT[gc * (long)R + row] = s;
  }
}

// ---------------------------------------------------------------------------
// int8 GEMM, 256x128 tile, BK=128 (= one quant group), 512 thr / 8 waves
// (4 wm x 2 wn; per-wave 64x64 output = r5's proven per-wave shape).
// LDS DOUBLE-BUFFER: stage(g+1) -> buf^1 issued BEFORE compute(g), one
// __syncthreads per group -- its vmcnt(0) drain lands ~2500 cyc after issue,
// so staging latency hides under MFMA instead of being exposed (r5's stall).
// G4 XOR swizzle both sides (verified r5: conflicts 1e8 -> 2e6). Exact int32
// MFMA per group, fp32 rescale with transposed contiguous scales.
// ---------------------------------------------------------------------------

// gu LDS map (bytes): buf b at b*65536: A@0 (32K), BG@32768 (16K), BU@49152.
// scales @131072 + b*2048: sSa(1024) sSg@+1024(512) sSu@+1536(512).
// rmx@135168 (2048), rs@137216 (1024). Total 138240.
#define GU_SC 131072
#define GU_RMX 135168
#define GU_RS 137216
#define GU_LDS 138240

// Fused gate/up GEMM + SwiGLU + hidden group-quant (group = tile's 128 cols).
__global__ __launch_bounds__(512, 2)
void gemm_gu_i8(const char* __restrict__ Aq, const char* __restrict__ Bg,
                const char* __restrict__ Bu,
                const float* __restrict__ sAT, const float* __restrict__ sGT,
                const float* __restrict__ sUT,
                char* __restrict__ Hq, float* __restrict__ sHT,
                int M, int N, int K, int NBN) {
  extern __shared__ __align__(16) char smem[];
  const int tid = threadIdx.x;
  const int lane = tid & 63;
  const int wid = tid >> 6;
  const int wm = wid >> 1, wn = wid & 1;
  const int wr = wm * 64, wc = wn * 64;
  const int l15 = lane & 15, l16 = lane >> 4;

  const int nwg = gridDim.x;
  const int wg = ((int)blockIdx.x & 7) * (nwg >> 3) + ((int)blockIdx.x >> 3);
  const long m0 = (long)(wg / NBN) * 256;
  const long n0 = (long)(wg % NBN) * 128;

  // staging: chunk c = tid + 512k -> row = (tid>>3) + 64k, swizzled col.
  const long rowS = tid >> 3;
  const int offS = ((tid & 7) * 16) ^ ((int)(rowS & 7) << 4);
  const long kstr = 64L * K;
  const char* gA0 = Aq + (m0 + rowS) * K + offS;   // k = 0..3
  const char* gG0 = Bg + (n0 + rowS) * K + offS;   // k = 0..1
  const char* gU0 = Bu + (n0 + rowS) * K + offS;

  const int rdSwz = (l15 & 7) << 4;
  const int colK0 = (l16 * 16) ^ rdSwz;
  const int colK1 = (64 + l16 * 16) ^ rdSwz;

  f32x4 accg[4][4], accu[4][4];
#pragma unroll
  for (int i = 0; i < 4; i++)
#pragma unroll
    for (int j = 0; j < 4; j++) {
      accg[i][j] = (f32x4){0.f, 0.f, 0.f, 0.f};
      accu[i][j] = (f32x4){0.f, 0.f, 0.f, 0.f};
    }
  const i32x4 iz = {0, 0, 0, 0};
  const int KG = K >> 7;

#define GU_STAGE(gg, bb)                                                      \
  {                                                                           \
    const long kb = (long)(gg) << 7;                                          \
    char* tb = smem + (bb) * 65536;                                           \
    _Pragma("unroll") for (int k = 0; k < 4; k++)                             \
        gl_lds16(gA0 + kb + k * kstr, tb + (tid + 512 * k) * 16);             \
    _Pragma("unroll") for (int k = 0; k < 2; k++) {                           \
      gl_lds16(gG0 + kb + k * kstr, tb + 32768 + (tid + 512 * k) * 16);       \
      gl_lds16(gU0 + kb + k * kstr, tb + 49152 + (tid + 512 * k) * 16);       \
    }                                                                         \
    char* sc = smem + GU_SC + (bb) * 2048;                                    \
    if (wid < 4) {                                                            \
      gl_lds4(sAT + (long)(gg) * M + m0 + tid, sc + wid * 256);               \
    } else if (wid < 6) {                                                     \
      gl_lds4(sGT + (long)(gg) * N + n0 + (tid - 256), sc + 1024 + (wid - 4) * 256); \
    } else {                                                                  \
      gl_lds4(sUT + (long)(gg) * N + n0 + (tid - 384), sc + 1536 + (wid - 6) * 256); \
    }                                                                         \
  }

  GU_STAGE(0, 0);
  __syncthreads();

  for (int g = 0; g < KG; ++g) {
    const int cb = g & 1;
    if (g + 1 < KG) GU_STAGE(g + 1, cb ^ 1);

    const char* tb = smem + cb * 65536;
    const float* sc = (const float*)(smem + GU_SC + cb * 2048);

    i32x4 af[4][2];
#pragma unroll
    for (int i = 0; i < 4; i++) {
      const int rb = (wr + i * 16 + l15) * 128;
      af[i][0] = *(const i32x4*)(tb + rb + colK0);
      af[i][1] = *(const i32x4*)(tb + rb + colK1);
    }
    f32x4 sa4[4];
#pragma unroll
    for (int i = 0; i < 4; i++)
      sa4[i] = *(const f32x4*)(sc + wr + i * 16 + l16 * 4);

#pragma unroll
    for (int j = 0; j < 4; j++) {
      const int rbB = (wc + j * 16 + l15) * 128;
      i32x4 bgf[2], buf_[2];
      bgf[0] = *(const i32x4*)(tb + 32768 + rbB + colK0);
      bgf[1] = *(const i32x4*)(tb + 32768 + rbB + colK1);
      buf_[0] = *(const i32x4*)(tb + 49152 + rbB + colK0);
      buf_[1] = *(const i32x4*)(tb + 49152 + rbB + colK1);
      float sbg = sc[256 + wc + j * 16 + l15];
      float sbu = sc[384 + wc + j * 16 + l15];
#pragma unroll
      for (int i = 0; i < 4; i++) {
        i32x4 tg = __builtin_amdgcn_mfma_i32_16x16x64_i8(af[i][0], bgf[0], iz, 0, 0, 0);
        tg = __builtin_amdgcn_mfma_i32_16x16x64_i8(af[i][1], bgf[1], tg, 0, 0, 0);
        i32x4 tu = __builtin_amdgcn_mfma_i32_16x16x64_i8(af[i][0], buf_[0], iz, 0, 0, 0);
        tu = __builtin_amdgcn_mfma_i32_16x16x64_i8(af[i][1], buf_[1], tu, 0, 0, 0);
        f32x4 mg = sa4[i] * sbg;
        f32x4 mu = sa4[i] * sbu;
        accg[i][j] += mg * __builtin_convertvector(tg, f32x4);
        accu[i][j] += mu * __builtin_convertvector(tu, f32x4);
      }
    }
    __syncthreads();  // drains vmcnt: stage(g+1) resident; all reads of cb done
  }

  // ---- epilogue: h = silu(g)*u; per-row (128-col group) max -> s; quantize.
  float* rmx = (float*)(smem + GU_RMX);  // [2][256]
  float* rs = (float*)(smem + GU_RS);    // [256]
  float pm[4][4];
#pragma unroll
  for (int i = 0; i < 4; i++)
#pragma unroll
    for (int r = 0; r < 4; r++) pm[i][r] = 0.f;
#pragma unroll
  for (int i = 0; i < 4; i++)
#pragma unroll
    for (int j = 0; j < 4; j++)
#pragma unroll
      for (int r = 0; r < 4; r++) {
        float gv = accg[i][j][r];
        float h = gv / (1.f + expf(-gv)) * accu[i][j][r];
        accu[i][j][r] = h;
        pm[i][r] = fmaxf(pm[i][r], fabsf(h));
      }
#pragma unroll
  for (int i = 0; i < 4; i++)
#pragma unroll
    for (int r = 0; r < 4; r++) {
      pm[i][r] = fmaxf(pm[i][r], __shfl_xor(pm[i][r], 1));
      pm[i][r] = fmaxf(pm[i][r], __shfl_xor(pm[i][r], 2));
      pm[i][r] = fmaxf(pm[i][r], __shfl_xor(pm[i][r], 4));
      pm[i][r] = fmaxf(pm[i][r], __shfl_xor(pm[i][r], 8));
    }
#pragma unroll
  for (int i = 0; i < 4; i++)
#pragma unroll
    for (int r = 0; r < 4; r++)
      if (l15 == i * 4 + r) rmx[wn * 256 + wr + i * 16 + l16 * 4 + r] = pm[i][r];
  __syncthreads();
  if (tid < 256) {
    float mx = fmaxf(rmx[tid], rmx[256 + tid]);
    float s = fmaxf(mx / QMAXF, EPSQ);
    rs[tid] = s;
    sHT[(n0 >> 7) * (long)M + m0 + tid] = s;
  }
  __syncthreads();
  // quantize into buf0-A region (K-loop done), then coalesced copy out
  char* sQ = smem;  // 256 rows x 128 B
#pragma unroll
  for (int i = 0; i < 4; i++) {
    f32x4 sr = *(const f32x4*)(rs + wr + i * 16 + l16 * 4);
#pragma unroll
    for (int j = 0; j < 4; j++)
#pragma unroll
      for (int r = 0; r < 4; r++) {
        float qv = fminf(fmaxf(rintf(accu[i][j][r] / sr[r]), -QMAXF), QMAXF);
        sQ[(wr + i * 16 + l16 * 4 + r) * 128 + wc + j * 16 + l15] = (char)(int)qv;
      }
  }
  __syncthreads();
  {
    int row = tid >> 1, seg = tid & 1;
    const i32x4* src = (const i32x4*)(sQ + row * 128 + seg * 64);
    i32x4* dst = (i32x4*)(Hq + (m0 + row) * N + n0 + seg * 64);
#pragma unroll
    for (int k = 0; k < 4; k++) dst[k] = src[k];
  }
}

// dn LDS map: buf b at b*49152: A@0 (32K), B@32768 (16K).
// scales @98304 + b*1536: sSa(1024) sSb@+1024(512). Total 101376.
#define DN_SC 98304
#define DN_LDS 101376

// Down GEMM: fp32 out = dequant(A_i8) . dequant(B_i8)^T with exact int cores.
__global__ __launch_bounds__(512, 2)
void gemm_dn_i8(const char* __restrict__ Aq, const char* __restrict__ Bq,
                const float* __restrict__ sAT, const float* __restrict__ sBT,
                float* __restrict__ C, int M, int N, int K, int NBN) {
  extern __shared__ __align__(16) char smem[];
  const int tid = threadIdx.x;
  const int lane = tid & 63;
  const int wid = tid >> 6;
  const int wm = wid >> 1, wn = wid & 1;
  const int wr = wm * 64, wc = wn * 64;
  const int l15 = lane & 15, l16 = lane >> 4;

  const int nwg = gridDim.x;
  const int wg = ((int)blockIdx.x & 7) * (nwg >> 3) + ((int)blockIdx.x >> 3);
  const long m0 = (long)(wg / NBN) * 256;
  const long n0 = (long)(wg % NBN) * 128;

  const long rowS = tid >> 3;
  const int offS = ((tid & 7) * 16) ^ ((int)(rowS & 7) << 4);
  const long kstr = 64L * K;
  const char* gA0 = Aq + (m0 + rowS) * K + offS;
  const char* gB0 = Bq + (n0 + rowS) * K + offS;

  const int rdSwz = (l15 & 7) << 4;
  const int colK0 = (l16 * 16) ^ rdSwz;
  const int colK1 = (64 + l16 * 16) ^ rdSwz;

  f32x4 acc[4][4];
#pragma unroll
  for (int i = 0; i < 4; i++)
#pragma unroll
    for (int j = 0; j < 4; j++) acc[i][j] = (f32x4){0.f, 0.f, 0.f, 0.f};
  const i32x4 iz = {0, 0, 0, 0};
  const int KG = K >> 7;

#define DN_STAGE(gg, bb)                                                      \
  {                                                                           \
    const long kb = (long)(gg) << 7;                                          \
    char* tb = smem + (bb) * 49152;                                           \
    _Pragma("unroll") for (int k = 0; k < 4; k++)                             \
        gl_lds16(gA0 + kb + k * kstr, tb + (tid + 512 * k) * 16);             \
    _Pragma("unroll") for (int k = 0; k < 2; k++)                             \
        gl_lds16(gB0 + kb + k * kstr, tb + 32768 + (tid + 512 * k) * 16);     \
    char* sc = smem + DN_SC + (bb) * 1536;                                    \
    if (wid < 4) {                                                            \
      gl_lds4(sAT + (long)(gg) * M + m0 + tid, sc + wid * 256);               \
    } else if (wid < 6) {                                                     \
      gl_lds4(sBT + (long)(gg) * N + n0 + (tid - 256), sc + 1024 + (wid - 4) * 256); \
    }                                                                         \
  }

  DN_STAGE(0, 0);
  __syncthreads();

  for (int g = 0; g < KG; ++g) {
    const int cb = g & 1;
    if (g + 1 < KG) DN_STAGE(g + 1, cb ^ 1);

    const char* tb = smem + cb * 49152;
    const float* sc = (const float*)(smem + DN_SC + cb * 1536);

    i32x4 af[4][2];
#pragma unroll
    for (int i = 0; i < 4; i++) {
      const int rb = (wr + i * 16 + l15) * 128;
      af[i][0] = *(const i32x4*)(tb + rb + colK0);
      af[i][1] = *(const i32x4*)(tb + rb + colK1);
    }
    f32x4 sa4[4];
#pragma unroll
    for (int i = 0; i < 4; i++)
      sa4[i] = *(const f32x4*)(sc + wr + i * 16 + l16 * 4);

#pragma unroll
    for (int j = 0; j < 4; j++) {
      const int rbB = (wc + j * 16 + l15) * 128;
      i32x4 bf[2];
      bf[0] = *(const i32x4*)(tb + 32768 + rbB + colK0);
      bf[1] = *(const i32x4*)(tb + 32768 + rbB + colK1);
      float sb = sc[256 + wc + j * 16 + l15];
#pragma unroll
      for (int i = 0; i < 4; i++) {
        i32x4 t = __builtin_amdgcn_mfma_i32_16x16x64_i8(af[i][0], bf[0], iz, 0, 0, 0);
        t = __builtin_amdgcn_mfma_i32_16x16x64_i8(af[i][1], bf[1], t, 0, 0, 0);
        f32x4 ms = sa4[i] * sb;
        acc[i][j] += ms * __builtin_convertvector(t, f32x4);
      }
    }
    __syncthreads();
  }

#pragma unroll
  for (int i = 0; i < 4; i++)
#pragma unroll
    for (int j = 0; j < 4; j++)
#pragma unroll
      for (int r = 0; r < 4; r++) {
        long row = m0 + wr + i * 16 + l16 * 4 + r;
        long col = n0 + wc + j * 16 + l15;
        C[row * N + col] = acc[i][j][r];
      }
}

extern "C" void kernel_launch(void* const* d_in, const int* in_sizes, int n_in,
                              void* d_out, int out_size, void* d_ws, size_t ws_size,
                              hipStream_t stream) {
  (void)n_in; (void)out_size;
  const float* x  = (const float*)d_in[0];
  const float* wg = (const float*)d_in[1];
  const float* wu = (const float*)d_in[2];
  const float* wd = (const float*)d_in[3];
  float* out = (float*)d_out;

  const long H = 4096;
  const long M = in_sizes[0] / H;   // 4096 (B*S)
  const long I = in_sizes[1] / H;   // 11008
  const long GH = H >> 7;           // 32
  const long GI = I >> 7;           // 86

  char* ws = (char*)d_ws;
  size_t off = 0;
  char* xq  = ws + off; off += (size_t)(M * H);
  char* wgq = ws + off; off += (size_t)(I * H);
  char* wuq = ws + off; off += (size_t)(I * H);
  char* wdq = ws + off; off += (size_t)(H * I);
  char* hq  = ws + off; off += (size_t)(M * I);
  float* s_x = (float*)(ws + off); off += (size_t)(GH * M) * 4;
  float* s_g = (float*)(ws + off); off += (size_t)(GH * I) * 4;
  float* s_u = (float*)(ws + off); off += (size_t)(GH * I) * 4;
  float* s_d = (float*)(ws + off); off += (size_t)(GI * H) * 4;
  float* s_h = (float*)(ws + off); off += (size_t)(GI * M) * 4;
  if (ws_size < off) return;

  hipFuncSetAttribute((const void*)gemm_gu_i8,
                      hipFuncAttributeMaxDynamicSharedMemorySize, GU_LDS);
  hipFuncSetAttribute((const void*)gemm_dn_i8,
                      hipFuncAttributeMaxDynamicSharedMemorySize, DN_LDS);

  // 1) int8 group-quant of inputs/weights (q + transposed scales)
  {
    long ng;
    ng = M * H / 128;
    qdq8<<<dim3((unsigned)((ng + 3) / 4)), dim3(256), 0, stream>>>(x, xq, s_x, ng, (int)GH, (int)M);
    ng = I * H / 128;
    qdq8<<<dim3((unsigned)((ng + 3) / 4)), dim3(256), 0, stream>>>(wg, wgq, s_g, ng, (int)GH, (int)I);
    qdq8<<<dim3((unsigned)((ng + 3) / 4)), dim3(256), 0, stream>>>(wu, wuq, s_u, ng, (int)GH, (int)I);
    ng = H * I / 128;
    qdq8<<<dim3((unsigned)((ng + 3) / 4)), dim3(256), 0, stream>>>(wd, wdq, s_d, ng, (int)GI, (int)H);
  }

  // 2) fused gate/up int8 GEMM + SwiGLU + hidden quant -> hq, s_h
  {
    const int NBN = (int)GI;                       // 86
    const int grid = (int)(M / 256) * NBN;         // 1376 (%8==0)
    gemm_gu_i8<<<dim3(grid), dim3(512), GU_LDS, stream>>>(
        xq, wgq, wuq, s_x, s_g, s_u, hq, s_h, (int)M, (int)I, (int)H, NBN);
  }
  // 3) down int8 GEMM -> fp32 out
  {
    const int NBN = (int)GH;                       // 32
    const int grid = (int)(M / 256) * NBN;         // 512 (%8==0)
    gemm_dn_i8<<<dim3(grid), dim3(512), DN_LDS, stream>>>(
        hq, wdq, s_h, s_d, out, (int)M, (int)H, (int)I, NBN);
  }
}